// Round 2
// baseline (278.602 us; speedup 1.0000x reference)
//
#include <hip/hip_runtime.h>

// BilinearMixture: out[e,c] = sum_d u[u_idx[e],d] * v[v_idx[e],d] * M[d,c]
//                           + u_bias[u_idx[e],c] + v_bias[v_idx[e],c]
// where M = W^T @ scalars ([64,5]) folds K=3 away.
//
// 16 lanes per edge: lane sl owns d = sl*4..sl*4+3 (one float4 per row ->
// each row read is a coalesced 256B wave-quarter). 5 accumulators are
// butterfly-reduced over the 16-lane group; lanes sl<5 emit the 5 classes.
// 2 edges per group-iteration for memory-level parallelism (gather-latency
// bound: tables are L2/L3-resident, so latency, not HBM BW, is the limit).

__global__ __launch_bounds__(256) void bilinear_edges(
    const float* __restrict__ u_feat, const float* __restrict__ v_feat,
    const float* __restrict__ W, const float* __restrict__ scalars,
    const float* __restrict__ u_bias, const float* __restrict__ v_bias,
    const int* __restrict__ u_idx, const int* __restrict__ v_idx,
    float* __restrict__ out, int E)
{
    const int tid    = blockIdx.x * blockDim.x + threadIdx.x;
    const int sl     = threadIdx.x & 15;          // lane within 16-lane group
    const int group  = tid >> 4;                  // global edge-group id
    const int ngroup = (gridDim.x * blockDim.x) >> 4;

    // Per-lane slice of M: m[j][c] = sum_k W[k][d0+j] * scalars[k][c]
    const int d0 = sl * 4;
    float m[4][5];
    {
        float w0[4], w1[4], w2[4];
        #pragma unroll
        for (int j = 0; j < 4; ++j) {
            w0[j] = W[0 * 64 + d0 + j];
            w1[j] = W[1 * 64 + d0 + j];
            w2[j] = W[2 * 64 + d0 + j];
        }
        #pragma unroll
        for (int c = 0; c < 5; ++c) {
            const float s0 = scalars[0 * 5 + c];
            const float s1 = scalars[1 * 5 + c];
            const float s2 = scalars[2 * 5 + c];
            #pragma unroll
            for (int j = 0; j < 4; ++j)
                m[j][c] = w0[j] * s0 + w1[j] * s1 + w2[j] * s2;
        }
    }

    for (int e0 = group * 2; e0 < E; e0 += ngroup * 2) {
        const int e1     = e0 + 1;
        const bool has1  = (e1 < E);

        // --- issue ALL index loads first (MLP) ---
        const int uu0 = u_idx[e0];
        const int vv0 = v_idx[e0];
        const int uu1 = has1 ? u_idx[e1] : uu0;
        const int vv1 = has1 ? v_idx[e1] : vv0;

        // --- issue all row gathers back-to-back ---
        const float4 u40 = *reinterpret_cast<const float4*>(u_feat + (size_t)uu0 * 64 + d0);
        const float4 v40 = *reinterpret_cast<const float4*>(v_feat + (size_t)vv0 * 64 + d0);
        const float4 u41 = *reinterpret_cast<const float4*>(u_feat + (size_t)uu1 * 64 + d0);
        const float4 v41 = *reinterpret_cast<const float4*>(v_feat + (size_t)vv1 * 64 + d0);

        // --- bias gathers issued early; latency hides under the butterfly ---
        float ub0 = 0.f, vb0 = 0.f, ub1 = 0.f, vb1 = 0.f;
        if (sl < 5) {
            ub0 = u_bias[(size_t)uu0 * 5 + sl];
            vb0 = v_bias[(size_t)vv0 * 5 + sl];
            ub1 = u_bias[(size_t)uu1 * 5 + sl];
            vb1 = v_bias[(size_t)vv1 * 5 + sl];
        }

        const float a0 = u40.x * v40.x, a1 = u40.y * v40.y,
                    a2 = u40.z * v40.z, a3 = u40.w * v40.w;
        const float b0 = u41.x * v41.x, b1 = u41.y * v41.y,
                    b2 = u41.z * v41.z, b3 = u41.w * v41.w;

        float accA[5], accB[5];
        #pragma unroll
        for (int c = 0; c < 5; ++c) {
            accA[c] = a0 * m[0][c] + a1 * m[1][c] + a2 * m[2][c] + a3 * m[3][c];
            accB[c] = b0 * m[0][c] + b1 * m[1][c] + b2 * m[2][c] + b3 * m[3][c];
        }

        // Butterfly over the 16-lane group; every lane ends with the full sum.
        #pragma unroll
        for (int mask = 1; mask < 16; mask <<= 1) {
            #pragma unroll
            for (int c = 0; c < 5; ++c) {
                accA[c] += __shfl_xor(accA[c], mask, 64);
                accB[c] += __shfl_xor(accB[c], mask, 64);
            }
        }

        if (sl < 5) {
            out[(size_t)e0 * 5 + sl] = accA[sl] + ub0 + vb0;
            if (has1)
                out[(size_t)e1 * 5 + sl] = accB[sl] + ub1 + vb1;
        }
    }
}

extern "C" void kernel_launch(void* const* d_in, const int* in_sizes, int n_in,
                              void* d_out, int out_size, void* d_ws, size_t ws_size,
                              hipStream_t stream) {
    const float* u_feat  = (const float*)d_in[0];
    const float* v_feat  = (const float*)d_in[1];
    const float* W       = (const float*)d_in[2];
    const float* scalars = (const float*)d_in[3];
    const float* u_bias  = (const float*)d_in[4];
    const float* v_bias  = (const float*)d_in[5];
    const int*   u_idx   = (const int*)d_in[6];
    const int*   v_idx   = (const int*)d_in[7];
    float*       out     = (float*)d_out;

    const int E = in_sizes[6];           // 2,000,000 edges

    const int threads = 256;
    const int blocks  = 4096;            // ~65k groups, ~15 edge-pairs each
    bilinear_edges<<<blocks, threads, 0, stream>>>(
        u_feat, v_feat, W, scalars, u_bias, v_bias, u_idx, v_idx, out, E);
}

// Round 3
// 243.611 us; speedup vs baseline: 1.1436x; 1.1436x over previous
//
#include <hip/hip_runtime.h>
#include <hip/hip_fp16.h>

// BilinearMixture: out[e,c] = sum_d u[uu,d]*v[vv,d]*M[d,c] + u_bias[uu,c] + v_bias[vv,c]
// with M = W^T @ scalars ([64,5]); K=3 folded away on the fly (fp32).
//
// R2 finding: gather-miss-bound (FETCH 640MB, VALU 24%, BW 44%). R3: gather
// tables converted to fp16 in d_ws each launch -> row = 128B = 1 cache line;
// halves gather bytes + L2-miss lines. Compute remains fp32.

// ---------- conversion: fp32 tables -> fp16 in workspace ----------
__global__ __launch_bounds__(256) void convert_tables_fp16(
    const float* __restrict__ u_feat, const float* __restrict__ v_feat,
    __half* __restrict__ u_h, __half* __restrict__ v_h, int nu, int nv)
{
    const int tid  = blockIdx.x * blockDim.x + threadIdx.x;
    const int nthr = gridDim.x * blockDim.x;
    for (int i = tid * 4; i < nu; i += nthr * 4) {
        const float4 x = *reinterpret_cast<const float4*>(u_feat + i);
        *reinterpret_cast<__half2*>(u_h + i)     = __floats2half2_rn(x.x, x.y);
        *reinterpret_cast<__half2*>(u_h + i + 2) = __floats2half2_rn(x.z, x.w);
    }
    for (int i = tid * 4; i < nv; i += nthr * 4) {
        const float4 x = *reinterpret_cast<const float4*>(v_feat + i);
        *reinterpret_cast<__half2*>(v_h + i)     = __floats2half2_rn(x.x, x.y);
        *reinterpret_cast<__half2*>(v_h + i + 2) = __floats2half2_rn(x.z, x.w);
    }
}

// ---------- main: fp16 gathers, fp32 math ----------
// 16 lanes/edge; lane sl owns d = sl*4..sl*4+3 (8B fp16 load per row ->
// group reads one contiguous 128B line per row). 2 edges per iteration for
// memory-level parallelism. Butterfly-reduce 5 accumulators over the group.
__global__ __launch_bounds__(256) void bilinear_edges_h(
    const __half* __restrict__ u_h, const __half* __restrict__ v_h,
    const float* __restrict__ W, const float* __restrict__ scalars,
    const float* __restrict__ u_bias, const float* __restrict__ v_bias,
    const int* __restrict__ u_idx, const int* __restrict__ v_idx,
    float* __restrict__ out, int E)
{
    const int tid    = blockIdx.x * blockDim.x + threadIdx.x;
    const int sl     = threadIdx.x & 15;
    const int group  = tid >> 4;
    const int ngroup = (gridDim.x * blockDim.x) >> 4;

    const int d0 = sl * 4;
    float m[4][5];
    {
        float w0[4], w1[4], w2[4];
        #pragma unroll
        for (int j = 0; j < 4; ++j) {
            w0[j] = W[0 * 64 + d0 + j];
            w1[j] = W[1 * 64 + d0 + j];
            w2[j] = W[2 * 64 + d0 + j];
        }
        #pragma unroll
        for (int c = 0; c < 5; ++c) {
            const float s0 = scalars[0 * 5 + c];
            const float s1 = scalars[1 * 5 + c];
            const float s2 = scalars[2 * 5 + c];
            #pragma unroll
            for (int j = 0; j < 4; ++j)
                m[j][c] = w0[j] * s0 + w1[j] * s1 + w2[j] * s2;
        }
    }

    for (int e0 = group * 2; e0 < E; e0 += ngroup * 2) {
        const int  e1   = e0 + 1;
        const bool has1 = (e1 < E);

        const int uu0 = u_idx[e0];
        const int vv0 = v_idx[e0];
        const int uu1 = has1 ? u_idx[e1] : uu0;
        const int vv1 = has1 ? v_idx[e1] : vv0;

        // 8B fp16 loads (one dwordx2 each); 4 rows in flight back-to-back.
        const float2 ur0 = *reinterpret_cast<const float2*>(u_h + (size_t)uu0 * 64 + d0);
        const float2 vr0 = *reinterpret_cast<const float2*>(v_h + (size_t)vv0 * 64 + d0);
        const float2 ur1 = *reinterpret_cast<const float2*>(u_h + (size_t)uu1 * 64 + d0);
        const float2 vr1 = *reinterpret_cast<const float2*>(v_h + (size_t)vv1 * 64 + d0);

        float ub0 = 0.f, vb0 = 0.f, ub1 = 0.f, vb1 = 0.f;
        if (sl < 5) {
            ub0 = u_bias[(size_t)uu0 * 5 + sl];
            vb0 = v_bias[(size_t)vv0 * 5 + sl];
            ub1 = u_bias[(size_t)uu1 * 5 + sl];
            vb1 = v_bias[(size_t)vv1 * 5 + sl];
        }

        const float2 u0a = __half22float2(*reinterpret_cast<const __half2*>(&ur0.x));
        const float2 u0b = __half22float2(*reinterpret_cast<const __half2*>(&ur0.y));
        const float2 v0a = __half22float2(*reinterpret_cast<const __half2*>(&vr0.x));
        const float2 v0b = __half22float2(*reinterpret_cast<const __half2*>(&vr0.y));
        const float2 u1a = __half22float2(*reinterpret_cast<const __half2*>(&ur1.x));
        const float2 u1b = __half22float2(*reinterpret_cast<const __half2*>(&ur1.y));
        const float2 v1a = __half22float2(*reinterpret_cast<const __half2*>(&vr1.x));
        const float2 v1b = __half22float2(*reinterpret_cast<const __half2*>(&vr1.y));

        const float a0 = u0a.x * v0a.x, a1 = u0a.y * v0a.y,
                    a2 = u0b.x * v0b.x, a3 = u0b.y * v0b.y;
        const float b0 = u1a.x * v1a.x, b1 = u1a.y * v1a.y,
                    b2 = u1b.x * v1b.x, b3 = u1b.y * v1b.y;

        float accA[5], accB[5];
        #pragma unroll
        for (int c = 0; c < 5; ++c) {
            accA[c] = a0 * m[0][c] + a1 * m[1][c] + a2 * m[2][c] + a3 * m[3][c];
            accB[c] = b0 * m[0][c] + b1 * m[1][c] + b2 * m[2][c] + b3 * m[3][c];
        }

        #pragma unroll
        for (int mask = 1; mask < 16; mask <<= 1) {
            #pragma unroll
            for (int c = 0; c < 5; ++c) {
                accA[c] += __shfl_xor(accA[c], mask, 64);
                accB[c] += __shfl_xor(accB[c], mask, 64);
            }
        }

        if (sl < 5) {
            out[(size_t)e0 * 5 + sl] = accA[sl] + ub0 + vb0;
            if (has1)
                out[(size_t)e1 * 5 + sl] = accB[sl] + ub1 + vb1;
        }
    }
}

// ---------- fallback: fp32 gathers (R2 kernel), used only if ws too small ----
__global__ __launch_bounds__(256) void bilinear_edges_f32(
    const float* __restrict__ u_feat, const float* __restrict__ v_feat,
    const float* __restrict__ W, const float* __restrict__ scalars,
    const float* __restrict__ u_bias, const float* __restrict__ v_bias,
    const int* __restrict__ u_idx, const int* __restrict__ v_idx,
    float* __restrict__ out, int E)
{
    const int tid    = blockIdx.x * blockDim.x + threadIdx.x;
    const int sl     = threadIdx.x & 15;
    const int group  = tid >> 4;
    const int ngroup = (gridDim.x * blockDim.x) >> 4;

    const int d0 = sl * 4;
    float m[4][5];
    {
        float w0[4], w1[4], w2[4];
        #pragma unroll
        for (int j = 0; j < 4; ++j) {
            w0[j] = W[0 * 64 + d0 + j];
            w1[j] = W[1 * 64 + d0 + j];
            w2[j] = W[2 * 64 + d0 + j];
        }
        #pragma unroll
        for (int c = 0; c < 5; ++c) {
            const float s0 = scalars[0 * 5 + c];
            const float s1 = scalars[1 * 5 + c];
            const float s2 = scalars[2 * 5 + c];
            #pragma unroll
            for (int j = 0; j < 4; ++j)
                m[j][c] = w0[j] * s0 + w1[j] * s1 + w2[j] * s2;
        }
    }

    for (int e0 = group * 2; e0 < E; e0 += ngroup * 2) {
        const int  e1   = e0 + 1;
        const bool has1 = (e1 < E);
        const int uu0 = u_idx[e0];
        const int vv0 = v_idx[e0];
        const int uu1 = has1 ? u_idx[e1] : uu0;
        const int vv1 = has1 ? v_idx[e1] : vv0;

        const float4 u40 = *reinterpret_cast<const float4*>(u_feat + (size_t)uu0 * 64 + d0);
        const float4 v40 = *reinterpret_cast<const float4*>(v_feat + (size_t)vv0 * 64 + d0);
        const float4 u41 = *reinterpret_cast<const float4*>(u_feat + (size_t)uu1 * 64 + d0);
        const float4 v41 = *reinterpret_cast<const float4*>(v_feat + (size_t)vv1 * 64 + d0);

        float ub0 = 0.f, vb0 = 0.f, ub1 = 0.f, vb1 = 0.f;
        if (sl < 5) {
            ub0 = u_bias[(size_t)uu0 * 5 + sl];
            vb0 = v_bias[(size_t)vv0 * 5 + sl];
            ub1 = u_bias[(size_t)uu1 * 5 + sl];
            vb1 = v_bias[(size_t)vv1 * 5 + sl];
        }

        const float a0 = u40.x * v40.x, a1 = u40.y * v40.y,
                    a2 = u40.z * v40.z, a3 = u40.w * v40.w;
        const float b0 = u41.x * v41.x, b1 = u41.y * v41.y,
                    b2 = u41.z * v41.z, b3 = u41.w * v41.w;

        float accA[5], accB[5];
        #pragma unroll
        for (int c = 0; c < 5; ++c) {
            accA[c] = a0 * m[0][c] + a1 * m[1][c] + a2 * m[2][c] + a3 * m[3][c];
            accB[c] = b0 * m[0][c] + b1 * m[1][c] + b2 * m[2][c] + b3 * m[3][c];
        }
        #pragma unroll
        for (int mask = 1; mask < 16; mask <<= 1) {
            #pragma unroll
            for (int c = 0; c < 5; ++c) {
                accA[c] += __shfl_xor(accA[c], mask, 64);
                accB[c] += __shfl_xor(accB[c], mask, 64);
            }
        }
        if (sl < 5) {
            out[(size_t)e0 * 5 + sl] = accA[sl] + ub0 + vb0;
            if (has1)
                out[(size_t)e1 * 5 + sl] = accB[sl] + ub1 + vb1;
        }
    }
}

extern "C" void kernel_launch(void* const* d_in, const int* in_sizes, int n_in,
                              void* d_out, int out_size, void* d_ws, size_t ws_size,
                              hipStream_t stream) {
    const float* u_feat  = (const float*)d_in[0];
    const float* v_feat  = (const float*)d_in[1];
    const float* W       = (const float*)d_in[2];
    const float* scalars = (const float*)d_in[3];
    const float* u_bias  = (const float*)d_in[4];
    const float* v_bias  = (const float*)d_in[5];
    const int*   u_idx   = (const int*)d_in[6];
    const int*   v_idx   = (const int*)d_in[7];
    float*       out     = (float*)d_out;

    const int nu = in_sizes[0];          // NUM_USERS * 64
    const int nv = in_sizes[1];          // NUM_ITEMS * 64
    const int E  = in_sizes[6];          // 2,000,000 edges

    const size_t ws_need = (size_t)(nu + nv) * sizeof(__half);

    if (ws_size >= ws_need) {
        __half* u_h = (__half*)d_ws;
        __half* v_h = u_h + nu;
        convert_tables_fp16<<<2048, 256, 0, stream>>>(u_feat, v_feat, u_h, v_h, nu, nv);
        bilinear_edges_h<<<2048, 256, 0, stream>>>(
            u_h, v_h, W, scalars, u_bias, v_bias, u_idx, v_idx, out, E);
    } else {
        bilinear_edges_f32<<<2048, 256, 0, stream>>>(
            u_feat, v_feat, W, scalars, u_bias, v_bias, u_idx, v_idx, out, E);
    }
}

// Round 4
// 208.030 us; speedup vs baseline: 1.3392x; 1.1710x over previous
//
#include <hip/hip_runtime.h>
#include <hip/hip_fp16.h>

// BilinearMixture: out[e,c] = sum_d u[uu,d]*v[vv,d]*M[d,c] + u_bias[uu,c] + v_bias[vv,c]
// R3 finding: DS-pipe bound — __shfl_xor butterfly (40 DS ops / 2 edges) was
// ~half the kernel. R4: (a) reduce K=3 basis partials instead of C=5 logits
// (scalars applied post-reduction), (b) DPP v_add (quad_perm/row_ror) instead
// of ds_swizzle — VALU-rate, zero DS traffic, (c) prefetch next indices.
// Tables remain fp16 in d_ws (row = 128B = 1 cache line).

template <int CTRL>
__device__ __forceinline__ float dpp_add(float x) {
    int t = __builtin_amdgcn_update_dpp(0, __float_as_int(x), CTRL, 0xF, 0xF, true);
    return x + __int_as_float(t);
}

// Sum (a,b,c) across each 16-lane group. xor1/xor2 via quad_perm, then
// row_ror:4 / row_ror:8 (rotations stay inside the 16-lane DPP row).
__device__ __forceinline__ void reduce16_3(float& a, float& b, float& c) {
    a = dpp_add<0xB1>(a);  b = dpp_add<0xB1>(b);  c = dpp_add<0xB1>(c);   // xor 1
    a = dpp_add<0x4E>(a);  b = dpp_add<0x4E>(b);  c = dpp_add<0x4E>(c);   // xor 2
    a = dpp_add<0x124>(a); b = dpp_add<0x124>(b); c = dpp_add<0x124>(c);  // ror 4
    a = dpp_add<0x128>(a); b = dpp_add<0x128>(b); c = dpp_add<0x128>(c);  // ror 8
}

// ---------- conversion: fp32 tables -> fp16 in workspace ----------
__global__ __launch_bounds__(256) void convert_tables_fp16(
    const float* __restrict__ u_feat, const float* __restrict__ v_feat,
    __half* __restrict__ u_h, __half* __restrict__ v_h, int nu, int nv)
{
    const int tid  = blockIdx.x * blockDim.x + threadIdx.x;
    const int nthr = gridDim.x * blockDim.x;
    for (int i = tid * 4; i < nu; i += nthr * 4) {
        const float4 x = *reinterpret_cast<const float4*>(u_feat + i);
        *reinterpret_cast<__half2*>(u_h + i)     = __floats2half2_rn(x.x, x.y);
        *reinterpret_cast<__half2*>(u_h + i + 2) = __floats2half2_rn(x.z, x.w);
    }
    for (int i = tid * 4; i < nv; i += nthr * 4) {
        const float4 x = *reinterpret_cast<const float4*>(v_feat + i);
        *reinterpret_cast<__half2*>(v_h + i)     = __floats2half2_rn(x.x, x.y);
        *reinterpret_cast<__half2*>(v_h + i + 2) = __floats2half2_rn(x.z, x.w);
    }
}

// ---------- main kernel ----------
// 16 lanes/edge; lane sl owns d = sl*4..sl*4+3 (8B fp16 load -> one 128B line
// per row per group). 2 edges per iteration for MLP; index prefetch one
// iteration ahead.
__global__ __launch_bounds__(256) void bilinear_edges_h(
    const __half* __restrict__ u_h, const __half* __restrict__ v_h,
    const float* __restrict__ W, const float* __restrict__ scalars,
    const float* __restrict__ u_bias, const float* __restrict__ v_bias,
    const int* __restrict__ u_idx, const int* __restrict__ v_idx,
    float* __restrict__ out, int E)
{
    const int tid    = blockIdx.x * blockDim.x + threadIdx.x;
    const int sl     = threadIdx.x & 15;
    const int group  = tid >> 4;
    const int ngroup = (gridDim.x * blockDim.x) >> 4;
    const int step   = ngroup * 2;

    // Per-lane W slice: w[k][j] = W[k, d0+j]  (12 regs)
    const int d0 = sl * 4;
    float w0[4], w1[4], w2[4];
    #pragma unroll
    for (int j = 0; j < 4; ++j) {
        w0[j] = W[0 * 64 + d0 + j];
        w1[j] = W[1 * 64 + d0 + j];
        w2[j] = W[2 * 64 + d0 + j];
    }
    // Writer lanes keep their scalars column (3 regs).
    float s0 = 0.f, s1 = 0.f, s2 = 0.f;
    if (sl < 5) { s0 = scalars[0 * 5 + sl]; s1 = scalars[1 * 5 + sl]; s2 = scalars[2 * 5 + sl]; }

    int e0 = group * 2;
    if (e0 >= E) return;

    // Prologue index load; loop prefetches the next pair.
    int uu0 = u_idx[e0];
    int vv0 = v_idx[e0];
    int uu1 = (e0 + 1 < E) ? u_idx[e0 + 1] : uu0;
    int vv1 = (e0 + 1 < E) ? v_idx[e0 + 1] : vv0;

    for (; e0 < E; e0 += step) {
        const int  e1   = e0 + 1;
        const bool has1 = (e1 < E);
        const int cu0 = uu0, cv0 = vv0, cu1 = uu1, cv1 = vv1;

        // Row gathers (4 independent 8B loads -> 4 lines in flight).
        const float2 ur0 = *reinterpret_cast<const float2*>(u_h + (size_t)cu0 * 64 + d0);
        const float2 vr0 = *reinterpret_cast<const float2*>(v_h + (size_t)cv0 * 64 + d0);
        const float2 ur1 = *reinterpret_cast<const float2*>(u_h + (size_t)cu1 * 64 + d0);
        const float2 vr1 = *reinterpret_cast<const float2*>(v_h + (size_t)cv1 * 64 + d0);

        // Prefetch next iteration's indices (hides idx->row chain hop).
        const int en = e0 + step;
        if (en < E) {
            uu0 = u_idx[en];
            vv0 = v_idx[en];
            const int en1 = en + 1;
            uu1 = (en1 < E) ? u_idx[en1] : uu0;
            vv1 = (en1 < E) ? v_idx[en1] : vv0;
        }

        // Bias gathers early (L2-resident; hide under compute).
        float ub0 = 0.f, vb0 = 0.f, ub1 = 0.f, vb1 = 0.f;
        if (sl < 5) {
            ub0 = u_bias[(size_t)cu0 * 5 + sl];
            vb0 = v_bias[(size_t)cv0 * 5 + sl];
            ub1 = u_bias[(size_t)cu1 * 5 + sl];
            vb1 = v_bias[(size_t)cv1 * 5 + sl];
        }

        const float2 u0a = __half22float2(*reinterpret_cast<const __half2*>(&ur0.x));
        const float2 u0b = __half22float2(*reinterpret_cast<const __half2*>(&ur0.y));
        const float2 v0a = __half22float2(*reinterpret_cast<const __half2*>(&vr0.x));
        const float2 v0b = __half22float2(*reinterpret_cast<const __half2*>(&vr0.y));
        const float2 u1a = __half22float2(*reinterpret_cast<const __half2*>(&ur1.x));
        const float2 u1b = __half22float2(*reinterpret_cast<const __half2*>(&ur1.y));
        const float2 v1a = __half22float2(*reinterpret_cast<const __half2*>(&vr1.x));
        const float2 v1b = __half22float2(*reinterpret_cast<const __half2*>(&vr1.y));

        const float a0 = u0a.x * v0a.x, a1 = u0a.y * v0a.y,
                    a2 = u0b.x * v0b.x, a3 = u0b.y * v0b.y;
        const float b0 = u1a.x * v1a.x, b1 = u1a.y * v1a.y,
                    b2 = u1b.x * v1b.x, b3 = u1b.y * v1b.y;

        // K=3 basis partials per lane (12 FMA per edge).
        float qa0 = a0*w0[0] + a1*w0[1] + a2*w0[2] + a3*w0[3];
        float qa1 = a0*w1[0] + a1*w1[1] + a2*w1[2] + a3*w1[3];
        float qa2 = a0*w2[0] + a1*w2[1] + a2*w2[2] + a3*w2[3];
        float qb0 = b0*w0[0] + b1*w0[1] + b2*w0[2] + b3*w0[3];
        float qb1 = b0*w1[0] + b1*w1[1] + b2*w1[2] + b3*w1[3];
        float qb2 = b0*w2[0] + b1*w2[1] + b2*w2[2] + b3*w2[3];

        // DPP reduction over the 16-lane group (VALU-rate, no DS pipe).
        reduce16_3(qa0, qa1, qa2);
        reduce16_3(qb0, qb1, qb2);

        if (sl < 5) {
            out[(size_t)e0 * 5 + sl] = qa0 * s0 + qa1 * s1 + qa2 * s2 + ub0 + vb0;
            if (has1)
                out[(size_t)e1 * 5 + sl] = qb0 * s0 + qb1 * s1 + qb2 * s2 + ub1 + vb1;
        }
    }
}

// ---------- fallback: fp32 gathers (only if ws too small; normally unused) ---
__global__ __launch_bounds__(256) void bilinear_edges_f32(
    const float* __restrict__ u_feat, const float* __restrict__ v_feat,
    const float* __restrict__ W, const float* __restrict__ scalars,
    const float* __restrict__ u_bias, const float* __restrict__ v_bias,
    const int* __restrict__ u_idx, const int* __restrict__ v_idx,
    float* __restrict__ out, int E)
{
    const int tid    = blockIdx.x * blockDim.x + threadIdx.x;
    const int sl     = threadIdx.x & 15;
    const int group  = tid >> 4;
    const int ngroup = (gridDim.x * blockDim.x) >> 4;

    const int d0 = sl * 4;
    float w0[4], w1[4], w2[4];
    #pragma unroll
    for (int j = 0; j < 4; ++j) {
        w0[j] = W[0 * 64 + d0 + j];
        w1[j] = W[1 * 64 + d0 + j];
        w2[j] = W[2 * 64 + d0 + j];
    }
    float s0 = 0.f, s1 = 0.f, s2 = 0.f;
    if (sl < 5) { s0 = scalars[0 * 5 + sl]; s1 = scalars[1 * 5 + sl]; s2 = scalars[2 * 5 + sl]; }

    for (int e = group; e < E; e += ngroup) {
        const int uu = u_idx[e];
        const int vv = v_idx[e];
        const float4 u4 = *reinterpret_cast<const float4*>(u_feat + (size_t)uu * 64 + d0);
        const float4 v4 = *reinterpret_cast<const float4*>(v_feat + (size_t)vv * 64 + d0);
        float ub = 0.f, vb = 0.f;
        if (sl < 5) { ub = u_bias[(size_t)uu * 5 + sl]; vb = v_bias[(size_t)vv * 5 + sl]; }

        const float p0 = u4.x * v4.x, p1 = u4.y * v4.y,
                    p2 = u4.z * v4.z, p3 = u4.w * v4.w;
        float q0 = p0*w0[0] + p1*w0[1] + p2*w0[2] + p3*w0[3];
        float q1 = p0*w1[0] + p1*w1[1] + p2*w1[2] + p3*w1[3];
        float q2 = p0*w2[0] + p1*w2[1] + p2*w2[2] + p3*w2[3];
        reduce16_3(q0, q1, q2);
        if (sl < 5)
            out[(size_t)e * 5 + sl] = q0 * s0 + q1 * s1 + q2 * s2 + ub + vb;
    }
}

extern "C" void kernel_launch(void* const* d_in, const int* in_sizes, int n_in,
                              void* d_out, int out_size, void* d_ws, size_t ws_size,
                              hipStream_t stream) {
    const float* u_feat  = (const float*)d_in[0];
    const float* v_feat  = (const float*)d_in[1];
    const float* W       = (const float*)d_in[2];
    const float* scalars = (const float*)d_in[3];
    const float* u_bias  = (const float*)d_in[4];
    const float* v_bias  = (const float*)d_in[5];
    const int*   u_idx   = (const int*)d_in[6];
    const int*   v_idx   = (const int*)d_in[7];
    float*       out     = (float*)d_out;

    const int nu = in_sizes[0];          // NUM_USERS * 64
    const int nv = in_sizes[1];          // NUM_ITEMS * 64
    const int E  = in_sizes[6];          // 2,000,000 edges

    const size_t ws_need = (size_t)(nu + nv) * sizeof(__half);

    if (ws_size >= ws_need) {
        __half* u_h = (__half*)d_ws;
        __half* v_h = u_h + nu;
        convert_tables_fp16<<<2048, 256, 0, stream>>>(u_feat, v_feat, u_h, v_h, nu, nv);
        bilinear_edges_h<<<2048, 256, 0, stream>>>(
            u_h, v_h, W, scalars, u_bias, v_bias, u_idx, v_idx, out, E);
    } else {
        bilinear_edges_f32<<<2048, 256, 0, stream>>>(
            u_feat, v_feat, W, scalars, u_bias, v_bias, u_idx, v_idx, out, E);
    }
}